// Round 1
// baseline (686.141 us; speedup 1.0000x reference)
//
#include <hip/hip_runtime.h>
#include <cstdint>
#include <cstddef>

typedef __attribute__((ext_vector_type(8))) short bf16x8;   // 8 bf16 = 4 VGPRs (per guide §3)
typedef __attribute__((ext_vector_type(4))) float floatx4;  // MFMA C/D frag

#define NBATCH 16
#define CIN    512
#define COUT   512
#define HH     64
#define WW     64
#define HP     66                 // padded H/W (+1 halo each side)
#define XSLOT  72                 // c-slot per (row,col): 64 data + 8 pad bf16 (144 B = 9*16B, kills bank conflicts)
#define XSZ    (4 * 66 * XSLOT)   // 19008 ushorts: X patch 4 rows x 66 cols x 64 c
#define ASZ    (128 * XSLOT)      // 9216 ushorts: W tile 128 o x 64 c

static __device__ __forceinline__ unsigned short f2bf(float f) {
  union { float f; unsigned u; } cv; cv.f = f;
  unsigned u = cv.u;
  return (unsigned short)((u + 0x7FFFu + ((u >> 16) & 1u)) >> 16);  // RNE
}

// K1: w2t[c][o] = sum_r w[o][c][r]^2 ; wr[r][o][c] = bf16(w[o][c][r])
__global__ void k_wprep(const float* __restrict__ w, unsigned short* __restrict__ wr,
                        float* __restrict__ w2t) {
  int o = blockIdx.x;
  int c = blockIdx.y * 256 + threadIdx.x;
  const float* wp = w + ((size_t)o * CIN + c) * 9;
  float v[9]; float sum = 0.f;
#pragma unroll
  for (int r = 0; r < 9; ++r) { v[r] = wp[r]; sum += v[r] * v[r]; }
  w2t[(size_t)c * COUT + o] = sum;
#pragma unroll
  for (int r = 0; r < 9; ++r)
    wr[((size_t)r * COUT + o) * CIN + c] = f2bf(v[r]);
}

// K2: d[n][o] = rsqrt(sum_c s[n][c]^2 * w2t[c][o] + 1e-8)   (fp32 exact path)
__global__ void k_dcoef(const float* __restrict__ s, const float* __restrict__ w2t,
                        float* __restrict__ d) {
  __shared__ float s2[CIN];
  int n = blockIdx.y;
  int o = blockIdx.x * 256 + threadIdx.x;
  for (int c = threadIdx.x; c < CIN; c += 256) {
    float sv = s[n * CIN + c]; s2[c] = sv * sv;
  }
  __syncthreads();
  float sum = 0.f;
  for (int c = 0; c < CIN; ++c) sum += s2[c] * w2t[(size_t)c * COUT + o];  // coalesced along o
  d[n * COUT + o] = rsqrtf(sum + 1e-8f);
}

// K3: xmp[n][h+1][w+1][c] = bf16(x[n][c][h][w] * s[n][c]); NHWC padded (borders pre-zeroed by memset)
__global__ void k_xmod(const float* __restrict__ x, const float* __restrict__ s,
                       unsigned short* __restrict__ xmp) {
  __shared__ __align__(16) unsigned short tile[WW * 520];   // [w][c], row stride 520 (1040 B, 16B-aligned)
  int tid  = threadIdx.x;
  int n    = blockIdx.x >> 6;
  int h    = blockIdx.x & 63;
  int wcol = tid & 63;
  int grp  = tid >> 6;
#pragma unroll
  for (int i = 0; i < 16; ++i) {        // each thread: 16 chunks of 8 channels for its w-column
    int c0 = (i * 4 + grp) * 8;
    bf16x8 pk;
#pragma unroll
    for (int j = 0; j < 8; ++j) {
      int c = c0 + j;
      float v = x[(((size_t)n * CIN + c) * HH + h) * WW + wcol] * s[n * CIN + c];  // lanes contiguous in w
      pk[j] = (short)f2bf(v);
    }
    *(bf16x8*)(tile + wcol * 520 + c0) = pk;   // b128 write, 8-phase minimum
  }
  __syncthreads();
#pragma unroll
  for (int i = 0; i < 16; ++i) {        // transpose out: lanes contiguous in c -> 1KB coalesced stores
    int wv = i * 4 + grp;
    bf16x8 v = *(const bf16x8*)(tile + wv * 520 + wcol * 8);
    *(bf16x8*)(xmp + (((size_t)n * HP + (h + 1)) * HP + (wv + 1)) * CIN + wcol * 8) = v;
  }
}

// Main: shift-GEMM modulated conv. Block = 256 thr (4 waves), tile 128 Cout x 128 pixels (2 rows x 64 w).
// GEMM C[o][p] = sum_c W_r[o][c] * X[c][p] accumulated over 9 shifts r=(kh,kw) and 8 c-blocks of 64.
// MFMA 16x16x32_bf16: A[m=lane&15][k=quad*8+j], B[k=quad*8+j][n=lane&15], D[m=quad*4+i][n=lane&15].
__global__ __launch_bounds__(256, 2)
void k_conv(const unsigned short* __restrict__ xmp, const unsigned short* __restrict__ wr,
            const float* __restrict__ d, const float* __restrict__ bias,
            const float* __restrict__ noise, float* __restrict__ out) {
  __shared__ __align__(16) unsigned short smem[XSZ + ASZ];  // 56448 B -> 2 blocks/CU
  unsigned short* Xs = smem;
  unsigned short* As = smem + XSZ;

  int tid  = threadIdx.x;
  int lane = tid & 63;
  int l15  = lane & 15;
  int quad = lane >> 4;
  int wv   = tid >> 6;
  int wrow = wv & 1;    // which of the 2 pixel rows this wave owns
  int woc  = wv >> 1;   // which 64-wide Cout half

  int bx  = blockIdx.x;
  int n   = bx >> 5;
  int h0  = (bx & 31) * 2;          // unpadded base row; padded patch rows = h0..h0+3
  int ocb = blockIdx.y * 128;

  floatx4 acc[4][4];
#pragma unroll
  for (int a = 0; a < 4; ++a)
#pragma unroll
    for (int b = 0; b < 4; ++b)
#pragma unroll
      for (int q = 0; q < 4; ++q) acc[a][b][q] = 0.f;

  for (int cb = 0; cb < 8; ++cb) {
    int c0 = cb * 64;
    // ---- stage X patch: 4 rows x 66 cols x 8 c-chunks = 2112 16B chunks (loads batched, then writes)
    {
      bf16x8 xv[8];
#pragma unroll
      for (int i = 0; i < 8; ++i) {
        int idx = i * 256 + tid;
        int row = idx / 528;                   // 528 = 66 cols * 8 chunks
        int rem = idx - row * 528;
        int col = rem >> 3, ch = rem & 7;
        xv[i] = *(const bf16x8*)(xmp + (((size_t)n * HP + (h0 + row)) * HP + col) * CIN + c0 + ch * 8);
      }
#pragma unroll
      for (int i = 0; i < 8; ++i) {
        int idx = i * 256 + tid;
        int row = idx / 528;
        int rem = idx - row * 528;
        int col = rem >> 3, ch = rem & 7;
        *(bf16x8*)(Xs + (row * 66 + col) * XSLOT + ch * 8) = xv[i];
      }
      if (tid < 64) {                          // tail: chunks 2048..2111 (row 3, cols 58..65)
        int rem = 464 + tid;
        int col = rem >> 3, ch = rem & 7;
        bf16x8 v = *(const bf16x8*)(xmp + (((size_t)n * HP + (h0 + 3)) * HP + col) * CIN + c0 + ch * 8);
        *(bf16x8*)(Xs + (3 * 66 + col) * XSLOT + ch * 8) = v;
      }
    }
    // ---- stage W(r=0)
#pragma unroll
    for (int i = 0; i < 4; ++i) {
      int idx = i * 256 + tid;
      int ol = idx >> 3, ch = idx & 7;
      bf16x8 v = *(const bf16x8*)(wr + ((size_t)(ocb + ol)) * CIN + c0 + ch * 8);
      *(bf16x8*)(As + ol * XSLOT + ch * 8) = v;
    }
    __syncthreads();

    for (int r = 0; r < 9; ++r) {
      // prefetch next W tile into registers; latency hidden behind this r's 32 MFMAs
      bf16x8 wpre[4];
      if (r < 8) {
#pragma unroll
        for (int i = 0; i < 4; ++i) {
          int idx = i * 256 + tid;
          int ol = idx >> 3, ch = idx & 7;
          wpre[i] = *(const bf16x8*)(wr + ((size_t)((r + 1) * COUT) + ocb + ol) * CIN + c0 + ch * 8);
        }
      }
      int kh = r / 3;
      int kw = r - kh * 3;
      int xrow = wrow + kh;
#pragma unroll
      for (int ks = 0; ks < 2; ++ks) {
        bf16x8 af[4], bfv[4];
#pragma unroll
        for (int mf = 0; mf < 4; ++mf)
          af[mf] = *(const bf16x8*)(As + (woc * 64 + mf * 16 + l15) * XSLOT + ks * 32 + quad * 8);
#pragma unroll
        for (int nf = 0; nf < 4; ++nf)
          bfv[nf] = *(const bf16x8*)(Xs + (xrow * 66 + (nf * 16 + l15 + kw)) * XSLOT + ks * 32 + quad * 8);
#pragma unroll
        for (int mf = 0; mf < 4; ++mf)
#pragma unroll
          for (int nf = 0; nf < 4; ++nf)
            acc[mf][nf] = __builtin_amdgcn_mfma_f32_16x16x32_bf16(af[mf], bfv[nf], acc[mf][nf], 0, 0, 0);
      }
      __syncthreads();                 // all waves done reading As for this r
      if (r < 8) {
#pragma unroll
        for (int i = 0; i < 4; ++i) {
          int idx = i * 256 + tid;
          int ol = idx >> 3, ch = idx & 7;
          *(bf16x8*)(As + ol * XSLOT + ch * 8) = wpre[i];
        }
        __syncthreads();               // W(r+1) visible before next compute
      }
    }
  }

  // ---- fused epilogue: out = leakyrelu(acc * d[n,o] + b[o] + noise)
  int h = h0 + wrow;
#pragma unroll
  for (int mf = 0; mf < 4; ++mf) {
#pragma unroll
    for (int i = 0; i < 4; ++i) {
      int o = ocb + woc * 64 + mf * 16 + quad * 4 + i;
      float dd = d[n * COUT + o];
      float bb = bias[o];
      size_t base = (((size_t)n * COUT + o) * HH + h) * WW;
#pragma unroll
      for (int nf = 0; nf < 4; ++nf) {
        int wc = nf * 16 + l15;        // lanes contiguous along w -> coalesced
        float v = acc[mf][nf][i] * dd + bb + noise[base + wc];
        out[base + wc] = (v >= 0.f) ? v : 0.2f * v;
      }
    }
  }
}

extern "C" void kernel_launch(void* const* d_in, const int* in_sizes, int n_in,
                              void* d_out, int out_size, void* d_ws, size_t ws_size,
                              hipStream_t stream) {
  (void)in_sizes; (void)n_in; (void)out_size; (void)ws_size;
  const float* x     = (const float*)d_in[0];
  const float* s     = (const float*)d_in[1];
  const float* noise = (const float*)d_in[2];
  const float* w     = (const float*)d_in[3];
  const float* bias  = (const float*)d_in[4];
  float* out = (float*)d_out;

  char* ws = (char*)d_ws;
  const size_t XMP_BYTES = (size_t)NBATCH * HP * HP * CIN * 2;  // 71,368,704
  const size_t WR_BYTES  = (size_t)9 * COUT * CIN * 2;          //  4,718,592
  const size_t W2_BYTES  = (size_t)CIN * COUT * 4;              //  1,048,576
  unsigned short* xmp = (unsigned short*)ws;
  unsigned short* wrr = (unsigned short*)(ws + XMP_BYTES);
  float* w2t          = (float*)(ws + XMP_BYTES + WR_BYTES);
  float* dcoef        = (float*)(ws + XMP_BYTES + WR_BYTES + W2_BYTES);
  // total workspace: 77,168,640 B

  hipMemsetAsync(xmp, 0, XMP_BYTES, stream);                       // zero halo borders
  k_wprep<<<dim3(COUT, 2),  256, 0, stream>>>(w, wrr, w2t);
  k_dcoef<<<dim3(2, NBATCH), 256, 0, stream>>>(s, w2t, dcoef);
  k_xmod <<<dim3(NBATCH * HH), 256, 0, stream>>>(x, s, xmp);
  k_conv <<<dim3(NBATCH * HH / 2, COUT / 128), 256, 0, stream>>>(xmp, wrr, dcoef, bias, noise, out);
}